// Round 12
// baseline (451.211 us; speedup 1.0000x reference)
//
#include <hip/hip_runtime.h>
#include <math.h>

typedef __attribute__((ext_vector_type(8))) short short8;
typedef __attribute__((ext_vector_type(4))) float f32x4;
typedef __attribute__((ext_vector_type(4))) _Float16 half4;
typedef __attribute__((ext_vector_type(8))) _Float16 half8;

#define N_SUBN   20000
#define E_EDGES  400000
#define R_REL    16
#define H_DIM    256
#define NBINS    (N_SUBN * R_REL)          // 320000 (dst,rel) buckets
#define SCAN_CHUNK 2048
#define NSCAN_BLOCKS ((NBINS + SCAN_CHUNK - 1) / SCAN_CHUNK)   // 157
#define NPAIRS   4096
#define TILE_N   32
#define NT_BLOCKS (N_SUBN / TILE_N)                            // 625 exact
#define D2       512
#define ECAP     1024                      // LDS edge-cache capacity (avg ~640/block)

// ---- bf16 hi/lo split helpers (RNE) ----
__device__ __forceinline__ ushort f2bf(float x) {
    uint u = __float_as_uint(x);
    u += 0x7fffu + ((u >> 16) & 1u);
    return (ushort)(u >> 16);
}
__device__ __forceinline__ float bf2f(ushort h) {
    return __uint_as_float(((uint)h) << 16);
}

// ---------------- gather: h0 = fp16(emb[node_ids]) ----------------
__global__ void k_gather(const float* __restrict__ emb, const int* __restrict__ nid,
                         _Float16* __restrict__ h0) {
    int t = blockIdx.x * blockDim.x + threadIdx.x;   // 20000*64 slots of 4 elems
    int node = t >> 6, c = (t & 63) << 2;
    if (node >= N_SUBN) return;
    const float4 s = *reinterpret_cast<const float4*>(emb + (size_t)nid[node] * H_DIM + c);
    half4 d = {(_Float16)s.x, (_Float16)s.y, (_Float16)s.z, (_Float16)s.w};
    *reinterpret_cast<half4*>(h0 + (size_t)node * H_DIM + c) = d;
}

// ---------------- CSR build over bin = dst*R + etype ----------------
__global__ void k_count(const int* __restrict__ dst, const int* __restrict__ ety,
                        int* __restrict__ cnt) {
    int e = blockIdx.x * 256 + threadIdx.x;
    if (e < E_EDGES) atomicAdd(&cnt[dst[e] * R_REL + ety[e]], 1);
}

__global__ void k_scan1(int* __restrict__ data, int* __restrict__ bs) {
    __shared__ int ts[256];
    int base = blockIdx.x * SCAN_CHUNK + threadIdx.x * 8;
    int v[8]; int s = 0;
#pragma unroll
    for (int j = 0; j < 8; j++) {
        int idx = base + j;
        v[j] = (idx < NBINS) ? data[idx] : 0;
        s += v[j];
    }
    ts[threadIdx.x] = s;
    __syncthreads();
    for (int off = 1; off < 256; off <<= 1) {
        int add = (threadIdx.x >= (unsigned)off) ? ts[threadIdx.x - off] : 0;
        __syncthreads();
        ts[threadIdx.x] += add;
        __syncthreads();
    }
    int excl = ts[threadIdx.x] - s;
    if (threadIdx.x == 255) bs[blockIdx.x] = ts[255];
    int run = excl;
#pragma unroll
    for (int j = 0; j < 8; j++) {
        int idx = base + j;
        if (idx < NBINS) data[idx] = run;
        run += v[j];
    }
}

__global__ void k_scan2(int* __restrict__ bs) {
    __shared__ int ls[NSCAN_BLOCKS];
    if (threadIdx.x < NSCAN_BLOCKS) ls[threadIdx.x] = bs[threadIdx.x];
    __syncthreads();
    if (threadIdx.x == 0) {
        int run = 0;
        for (int i = 0; i < NSCAN_BLOCKS; i++) { int t = ls[i]; ls[i] = run; run += t; }
    }
    __syncthreads();
    if (threadIdx.x < NSCAN_BLOCKS) bs[threadIdx.x] = ls[threadIdx.x];
}

__global__ void k_scan3(int* __restrict__ data, const int* __restrict__ bs) {
    int idx = blockIdx.x * 256 + threadIdx.x;
    if (idx < NBINS) data[idx] = data[idx] + bs[idx / SCAN_CHUNK];
}

// scatter increments segend in place: post-scatter segend[bin] = END of bin,
// beg(bin) = (bin==0) ? 0 : segend[bin-1]. Edge packed: (src<<17) | norm_q17.
__global__ void k_scatter(const int* __restrict__ src, const int* __restrict__ dst,
                          const int* __restrict__ ety, const float* __restrict__ nrm,
                          int* __restrict__ segend, uint* __restrict__ es) {
    int e = blockIdx.x * 256 + threadIdx.x;
    if (e >= E_EDGES) return;
    int bin = dst[e] * R_REL + ety[e];
    int pos = atomicAdd(&segend[bin], 1);
    float n = nrm[e];
    uint q = (uint)fminf(n * 131072.f + 0.5f, 131071.f);
    es[pos] = ((uint)src[e] << 17) | q;
}

// ---------------- combined pre-pack + segend zero (one dispatch) ----------------
__device__ __forceinline__ void prep_w_body(const float* __restrict__ w,
                                            ushort* __restrict__ wfrag, int t) {
    int lane = t & 63, f = t >> 6;
    int ot = f & 1, rb = f >> 1;              // rb = r*8+b
    int kbase = (lane >> 4) * 8, n = ot * 16 + (lane & 15);
    ushort hv[8], lv[8];
#pragma unroll
    for (int j = 0; j < 8; j++) {
        float x = w[(size_t)(rb * 32 + kbase + j) * 32 + n];
        ushort h = f2bf(x);
        ushort l = f2bf(x - bf2f(h));
        hv[j] = h; lv[j] = l;
    }
    *reinterpret_cast<short8*>(wfrag + ((size_t)(f * 2 + 0) * 64 + lane) * 8) =
        *reinterpret_cast<short8*>(hv);
    *reinterpret_cast<short8*>(wfrag + ((size_t)(f * 2 + 1) * 64 + lane) * 8) =
        *reinterpret_cast<short8*>(lv);
}

__device__ __forceinline__ void prep_lw_body(const float* __restrict__ lw,
                                             ushort* __restrict__ lwfrag, int t) {
    int lane = t & 63, g = t >> 6;
    int kt = g >> 4, ot = g & 15;
    int kbase = kt * 32 + (lane >> 4) * 8, n = ot * 16 + (lane & 15);
    ushort hv[8], lv[8];
#pragma unroll
    for (int j = 0; j < 8; j++) {
        float x = lw[(size_t)(kbase + j) * H_DIM + n];
        ushort h = f2bf(x);
        ushort l = f2bf(x - bf2f(h));
        hv[j] = h; lv[j] = l;
    }
    *reinterpret_cast<short8*>(lwfrag + ((size_t)(g * 2 + 0) * 64 + lane) * 8) =
        *reinterpret_cast<short8*>(hv);
    *reinterpret_cast<short8*>(lwfrag + ((size_t)(g * 2 + 1) * 64 + lane) * 8) =
        *reinterpret_cast<short8*>(lv);
}

__device__ __forceinline__ void prep_fc1_body(const float* __restrict__ w,
                                              ushort* __restrict__ wfrag, int t) {
    int lane = t & 63, g = t >> 6;
    int kt = g >> 5, ot = g & 31;
    int kbase = kt * 32 + (lane >> 4) * 8, n = ot * 16 + (lane & 15);
    ushort hv[8], lv[8];
#pragma unroll
    for (int j = 0; j < 8; j++) {
        float x = w[(size_t)(kbase + j) * D2 + n];
        ushort h = f2bf(x);
        ushort l = f2bf(x - bf2f(h));
        hv[j] = h; lv[j] = l;
    }
    *reinterpret_cast<short8*>(wfrag + ((size_t)(g * 2 + 0) * 64 + lane) * 8) =
        *reinterpret_cast<short8*>(hv);
    *reinterpret_cast<short8*>(wfrag + ((size_t)(g * 2 + 1) * 64 + lane) * 8) =
        *reinterpret_cast<short8*>(lv);
}

#define ZBLOCKS ((NBINS + 255) / 256)   // 1250

__global__ void k_prep_all(const float* __restrict__ w1, const float* __restrict__ w2,
                           const float* __restrict__ lw1, const float* __restrict__ lw2,
                           const float* __restrict__ fc1W,
                           ushort* __restrict__ wfrag1, ushort* __restrict__ wfrag2,
                           ushort* __restrict__ lwfrag1, ushort* __restrict__ lwfrag2,
                           ushort* __restrict__ fc1frag, int* __restrict__ segend) {
    int b = blockIdx.x, tid = threadIdx.x;
    if (b < 64)        prep_w_body(w1, wfrag1, b * 256 + tid);
    else if (b < 128)  prep_w_body(w2, wfrag2, (b - 64) * 256 + tid);
    else if (b < 160)  prep_lw_body(lw1, lwfrag1, (b - 128) * 256 + tid);
    else if (b < 192)  prep_lw_body(lw2, lwfrag2, (b - 160) * 256 + tid);
    else if (b < 320)  prep_fc1_body(fc1W, fc1frag, (b - 192) * 256 + tid);
    else {
        int i = (b - 320) * 256 + tid;
        if (i < NBINS) segend[i] = 0;
    }
}

// ---------------- fused RGCN-BDD layer (MFMA, bf16 hi/lo 3-term) ----------------
// Round-11 structure (TILE 32, 512 thr = 8 waves, LDS edge cache, single agg
// buffer, 2 barriers/rel, fp16 h) + REGISTER PREFETCH: the first 2 edges of each
// of the wave's 4 chains for rel r+1 are loaded into explicit scalar registers
// right after barrier1 of rel r — their latency hides under rel r's MFMA +
// barrier. 87% of bins have deg<=2 (Poisson 1.25); deg>=3 leftovers take the
// serial path. Self-loop rows prefetch during the last relation's MFMA.
__global__ __launch_bounds__(512) void k_layer(
    const _Float16* __restrict__ hin, const uint* __restrict__ es,
    const int* __restrict__ segend,
    const ushort* __restrict__ wfrag, const ushort* __restrict__ lwfrag,
    const float* __restrict__ bias, _Float16* __restrict__ hout) {
    __shared__ __align__(16) ushort aggH[TILE_N * H_DIM];
    __shared__ __align__(16) ushort aggLo[TILE_N * H_DIM];
    __shared__ int lofs[TILE_N * R_REL + 1];
    __shared__ uint les[ECAP];
    char* cH = (char*)aggH;
    char* cL = (char*)aggLo;
    const int n0 = blockIdx.x * TILE_N;
    const int tid = threadIdx.x;
    const int lane = tid & 63, wv = tid >> 6;
    const int col = lane & 15, kg = lane >> 4;
    const short8* wf  = (const short8*)wfrag;
    const short8* lwf = (const short8*)lwfrag;
    const uint laneoff = (uint)(lane << 2);     // element offset (4 fp16 per lane)
    const int t0 = 4 * wv;

    {   // block-local offset table (coalesced, once)
        const int base = n0 * R_REL;
        for (int j = tid; j < TILE_N * R_REL + 1; j += 512) {
            int g = base + j - 1;
            lofs[j] = (g < 0) ? 0 : segend[g];
        }
    }
    __syncthreads();
    const int ebase = lofs[0];
    const int elim  = min(lofs[TILE_N * R_REL] - ebase, ECAP);
    for (int j = tid; j < elim; j += 512) les[j] = es[ebase + j];
    __syncthreads();   // les published

    // edge word fetch (LDS cache w/ global fallback)
    auto eget = [&](int e) -> uint {
        int i = e - ebase;
        return (i < ECAP) ? les[i] : es[e];
    };
    auto rowload = [&](uint pk) -> half4 {
        return *reinterpret_cast<const half4*>(hin + (size_t)(pk >> 17) * H_DIM + laneoff);
    };

    f32x4 acc[2][2];
#pragma unroll
    for (int mt = 0; mt < 2; ++mt)
#pragma unroll
        for (int ot = 0; ot < 2; ++ot) acc[mt][ot] = (f32x4){0.f, 0.f, 0.f, 0.f};

    // prefetch state: 2 edges per chain, explicit scalars (no runtime indexing)
    int pb0, pe0, pb1, pe1, pb2, pe2, pb3, pe3;
    uint w0a = 0, w0b = 0, w1a = 0, w1b = 0, w2a = 0, w2b = 0, w3a = 0, w3b = 0;
    half4 x0a = {}, x0b = {}, x1a = {}, x1b = {}, x2a = {}, x2b = {}, x3a = {}, x3b = {};
    half4 sx0 = {}, sx1 = {}, sx2 = {}, sx3 = {};

    auto issue_prefetch = [&](int rr) {
        pb0 = lofs[(t0 + 0) * R_REL + rr]; pe0 = lofs[(t0 + 0) * R_REL + rr + 1];
        pb1 = lofs[(t0 + 1) * R_REL + rr]; pe1 = lofs[(t0 + 1) * R_REL + rr + 1];
        pb2 = lofs[(t0 + 2) * R_REL + rr]; pe2 = lofs[(t0 + 2) * R_REL + rr + 1];
        pb3 = lofs[(t0 + 3) * R_REL + rr]; pe3 = lofs[(t0 + 3) * R_REL + rr + 1];
        if (pb0 < pe0)     { w0a = eget(pb0);     x0a = rowload(w0a); }
        if (pb0 + 1 < pe0) { w0b = eget(pb0 + 1); x0b = rowload(w0b); }
        if (pb1 < pe1)     { w1a = eget(pb1);     x1a = rowload(w1a); }
        if (pb1 + 1 < pe1) { w1b = eget(pb1 + 1); x1b = rowload(w1b); }
        if (pb2 < pe2)     { w2a = eget(pb2);     x2a = rowload(w2a); }
        if (pb2 + 1 < pe2) { w2b = eget(pb2 + 1); x2b = rowload(w2b); }
        if (pb3 < pe3)     { w3a = eget(pb3);     x3a = rowload(w3a); }
        if (pb3 + 1 < pe3) { w3b = eget(pb3 + 1); x3b = rowload(w3b); }
    };

    issue_prefetch(0);

    for (int r = 0; r < R_REL; ++r) {
        // ---- consume prefetched edges + serial leftovers (deg>=3, rare) ----
        float4 a0 = make_float4(0.f, 0.f, 0.f, 0.f);
        float4 a1 = make_float4(0.f, 0.f, 0.f, 0.f);
        float4 a2 = make_float4(0.f, 0.f, 0.f, 0.f);
        float4 a3 = make_float4(0.f, 0.f, 0.f, 0.f);
        if (pb0 < pe0) {
            float nm = (float)(w0a & 0x1FFFFu) * (1.f / 131072.f);
            a0.x = fmaf((float)x0a[0], nm, a0.x); a0.y = fmaf((float)x0a[1], nm, a0.y);
            a0.z = fmaf((float)x0a[2], nm, a0.z); a0.w = fmaf((float)x0a[3], nm, a0.w);
        }
        if (pb0 + 1 < pe0) {
            float nm = (float)(w0b & 0x1FFFFu) * (1.f / 131072.f);
            a0.x = fmaf((float)x0b[0], nm, a0.x); a0.y = fmaf((float)x0b[1], nm, a0.y);
            a0.z = fmaf((float)x0b[2], nm, a0.z); a0.w = fmaf((float)x0b[3], nm, a0.w);
        }
        for (int e = pb0 + 2; e < pe0; ++e) {
            uint pk = eget(e); half4 x = rowload(pk);
            float nm = (float)(pk & 0x1FFFFu) * (1.f / 131072.f);
            a0.x = fmaf((float)x[0], nm, a0.x); a0.y = fmaf((float)x[1], nm, a0.y);
            a0.z = fmaf((float)x[2], nm, a0.z); a0.w = fmaf((float)x[3], nm, a0.w);
        }
        if (pb1 < pe1) {
            float nm = (float)(w1a & 0x1FFFFu) * (1.f / 131072.f);
            a1.x = fmaf((float)x1a[0], nm, a1.x); a1.y = fmaf((float)x1a[1], nm, a1.y);
            a1.z = fmaf((float)x1a[2], nm, a1.z); a1.w = fmaf((float)x1a[3], nm, a1.w);
        }
        if (pb1 + 1 < pe1) {
            float nm = (float)(w1b & 0x1FFFFu) * (1.f / 131072.f);
            a1.x = fmaf((float)x1b[0], nm, a1.x); a1.y = fmaf((float)x1b[1], nm, a1.y);
            a1.z = fmaf((float)x1b[2], nm, a1.z); a1.w = fmaf((float)x1b[3], nm, a1.w);
        }
        for (int e = pb1 + 2; e < pe1; ++e) {
            uint pk = eget(e); half4 x = rowload(pk);
            float nm = (float)(pk & 0x1FFFFu) * (1.f / 131072.f);
            a1.x = fmaf((float)x[0], nm, a1.x); a1.y = fmaf((float)x[1], nm, a1.y);
            a1.z = fmaf((float)x[2], nm, a1.z); a1.w = fmaf((float)x[3], nm, a1.w);
        }
        if (pb2 < pe2) {
            float nm = (float)(w2a & 0x1FFFFu) * (1.f / 131072.f);
            a2.x = fmaf((float)x2a[0], nm, a2.x); a2.y = fmaf((float)x2a[1], nm, a2.y);
            a2.z = fmaf((float)x2a[2], nm, a2.z); a2.w = fmaf((float)x2a[3], nm, a2.w);
        }
        if (pb2 + 1 < pe2) {
            float nm = (float)(w2b & 0x1FFFFu) * (1.f / 131072.f);
            a2.x = fmaf((float)x2b[0], nm, a2.x); a2.y = fmaf((float)x2b[1], nm, a2.y);
            a2.z = fmaf((float)x2b[2], nm, a2.z); a2.w = fmaf((float)x2b[3], nm, a2.w);
        }
        for (int e = pb2 + 2; e < pe2; ++e) {
            uint pk = eget(e); half4 x = rowload(pk);
            float nm = (float)(pk & 0x1FFFFu) * (1.f / 131072.f);
            a2.x = fmaf((float)x[0], nm, a2.x); a2.y = fmaf((float)x[1], nm, a2.y);
            a2.z = fmaf((float)x[2], nm, a2.z); a2.w = fmaf((float)x[3], nm, a2.w);
        }
        if (pb3 < pe3) {
            float nm = (float)(w3a & 0x1FFFFu) * (1.f / 131072.f);
            a3.x = fmaf((float)x3a[0], nm, a3.x); a3.y = fmaf((float)x3a[1], nm, a3.y);
            a3.z = fmaf((float)x3a[2], nm, a3.z); a3.w = fmaf((float)x3a[3], nm, a3.w);
        }
        if (pb3 + 1 < pe3) {
            float nm = (float)(w3b & 0x1FFFFu) * (1.f / 131072.f);
            a3.x = fmaf((float)x3b[0], nm, a3.x); a3.y = fmaf((float)x3b[1], nm, a3.y);
            a3.z = fmaf((float)x3b[2], nm, a3.z); a3.w = fmaf((float)x3b[3], nm, a3.w);
        }
        for (int e = pb3 + 2; e < pe3; ++e) {
            uint pk = eget(e); half4 x = rowload(pk);
            float nm = (float)(pk & 0x1FFFFu) * (1.f / 131072.f);
            a3.x = fmaf((float)x[0], nm, a3.x); a3.y = fmaf((float)x[1], nm, a3.y);
            a3.z = fmaf((float)x[2], nm, a3.z); a3.w = fmaf((float)x[3], nm, a3.w);
        }
        // ---- split + store rows to swizzled LDS planes ----
#pragma unroll
        for (int i = 0; i < 4; ++i) {
            float4 av = (i == 0) ? a0 : (i == 1) ? a1 : (i == 2) ? a2 : a3;
            int t = t0 + i;
            ushort h0 = f2bf(av.x), h1 = f2bf(av.y), h2 = f2bf(av.z), h3 = f2bf(av.w);
            uint2 ph = make_uint2((uint)h0 | ((uint)h1 << 16), (uint)h2 | ((uint)h3 << 16));
            uint2 pl = make_uint2(
                (uint)f2bf(av.x - bf2f(h0)) | ((uint)f2bf(av.y - bf2f(h1)) << 16),
                (uint)f2bf(av.z - bf2f(h2)) | ((uint)f2bf(av.w - bf2f(h3)) << 16));
            uint byte = (uint)(t * 512) + ((((lane >> 1) ^ (t & 7)) << 4) | ((lane & 1) << 3));
            *(uint2*)(cH + byte) = ph;
            *(uint2*)(cL + byte) = pl;
        }
        __syncthreads();   // barrier1: agg stores visible
        // ---- issue prefetch for next phase (hides under MFMA + barrier) ----
        if (r < R_REL - 1) {
            issue_prefetch(r + 1);
        } else {
            sx0 = *reinterpret_cast<const half4*>(hin + (size_t)(n0 + t0 + 0) * H_DIM + laneoff);
            sx1 = *reinterpret_cast<const half4*>(hin + (size_t)(n0 + t0 + 1) * H_DIM + laneoff);
            sx2 = *reinterpret_cast<const half4*>(hin + (size_t)(n0 + t0 + 2) * H_DIM + laneoff);
            sx3 = *reinterpret_cast<const half4*>(hin + (size_t)(n0 + t0 + 3) * H_DIM + laneoff);
        }
        // ---- transform rel r: wave wv owns b-block wv ----
#pragma unroll
        for (int ot = 0; ot < 2; ++ot) {
            int f = (r * 8 + wv) * 2 + ot;
            short8 Bh = wf[(f * 2 + 0) * 64 + lane];
            short8 Bl = wf[(f * 2 + 1) * 64 + lane];
#pragma unroll
            for (int mt = 0; mt < 2; ++mt) {
                int row = mt * 16 + col;
                uint ab = (uint)(row * 512) + ((uint)((wv * 4 + kg) ^ (row & 7)) << 4);
                short8 Ah = *(const short8*)(cH + ab);
                short8 Al = *(const short8*)(cL + ab);
                f32x4 a = acc[mt][ot];
                a = __builtin_amdgcn_mfma_f32_16x16x32_bf16(Ah, Bh, a, 0, 0, 0);
                a = __builtin_amdgcn_mfma_f32_16x16x32_bf16(Ah, Bl, a, 0, 0, 0);
                a = __builtin_amdgcn_mfma_f32_16x16x32_bf16(Al, Bh, a, 0, 0, 0);
                acc[mt][ot] = a;
            }
        }
        __syncthreads();   // barrier2: MFMA reads done before next agg store
    }

    // ---- self-loop: stage prefetched own rows, K=256 MFMA sweep ----
#pragma unroll
    for (int i = 0; i < 4; ++i) {
        half4 xh = (i == 0) ? sx0 : (i == 1) ? sx1 : (i == 2) ? sx2 : sx3;
        int t = t0 + i;
        float4 xv = make_float4((float)xh[0], (float)xh[1], (float)xh[2], (float)xh[3]);
        ushort h0 = f2bf(xv.x), h1 = f2bf(xv.y), h2 = f2bf(xv.z), h3 = f2bf(xv.w);
        uint2 ph = make_uint2((uint)h0 | ((uint)h1 << 16), (uint)h2 | ((uint)h3 << 16));
        uint2 pl = make_uint2(
            (uint)f2bf(xv.x - bf2f(h0)) | ((uint)f2bf(xv.y - bf2f(h1)) << 16),
            (uint)f2bf(xv.z - bf2f(h2)) | ((uint)f2bf(xv.w - bf2f(h3)) << 16));
        uint byte = (uint)(t * 512) + ((((lane >> 1) ^ (t & 7)) << 4) | ((lane & 1) << 3));
        *(uint2*)(cH + byte) = ph;
        *(uint2*)(cL + byte) = pl;
    }
    __syncthreads();
#pragma unroll
    for (int kt = 0; kt < 8; ++kt) {
#pragma unroll
        for (int ot = 0; ot < 2; ++ot) {
            int g = kt * 16 + 2 * wv + ot;
            short8 Bh = lwf[(g * 2 + 0) * 64 + lane];
            short8 Bl = lwf[(g * 2 + 1) * 64 + lane];
#pragma unroll
            for (int mt = 0; mt < 2; ++mt) {
                int row = mt * 16 + col;
                uint ab = (uint)(row * 512) + ((uint)((kt * 4 + kg) ^ (row & 7)) << 4);
                short8 Ah = *(const short8*)(cH + ab);
                short8 Al = *(const short8*)(cL + ab);
                f32x4 a = acc[mt][ot];
                a = __builtin_amdgcn_mfma_f32_16x16x32_bf16(Ah, Bh, a, 0, 0, 0);
                a = __builtin_amdgcn_mfma_f32_16x16x32_bf16(Ah, Bl, a, 0, 0, 0);
                a = __builtin_amdgcn_mfma_f32_16x16x32_bf16(Al, Bh, a, 0, 0, 0);
                acc[mt][ot] = a;
            }
        }
    }

    // ---- epilogue: C/D layout col=lane&15, row=(lane>>4)*4+reg; fp16 store ----
#pragma unroll
    for (int mt = 0; mt < 2; ++mt) {
        int nbase = n0 + mt * 16 + kg * 4;
#pragma unroll
        for (int ot = 0; ot < 2; ++ot) {
            int o = 32 * wv + ot * 16 + col;
            float bo = bias[o];
#pragma unroll
            for (int rg = 0; rg < 4; ++rg)
                hout[(size_t)(nbase + rg) * H_DIM + o] = (_Float16)(acc[mt][ot][rg] + bo);
        }
    }
}

// ---------------- fused concat + fc1(MFMA) + relu + fc2 + sigmoid ----------------
__global__ __launch_bounds__(512) void k_mlp(
    const _Float16* __restrict__ h, const int* __restrict__ drugs,
    const int* __restrict__ targets,
    const ushort* __restrict__ fc1frag, const float* __restrict__ b1f,
    const float* __restrict__ W2, const float* __restrict__ b2f,
    float* __restrict__ outp) {
    __shared__ __align__(16) ushort xH[16 * D2];
    __shared__ __align__(16) ushort xL[16 * D2];
    __shared__ float red[16][8];
    char* cH = (char*)xH;
    char* cL = (char*)xL;
    const int tid = threadIdx.x;
    const int lane = tid & 63, wv = tid >> 6;
    const int col = lane & 15, kg = lane >> 4;
    const int p0 = blockIdx.x * 16;
    const short8* wf = (const short8*)fc1frag;

    {   // stage X = [h[drug] | h[target]] (fp16) as bf16 hi/lo, swizzled
        int p = tid >> 5;
        int cc = (tid & 31) * 16;
        int di = drugs[p0 + p], ti = targets[p0 + p];
        const _Float16* srcp = (cc < H_DIM) ? (h + (size_t)di * H_DIM + cc)
                                            : (h + (size_t)ti * H_DIM + (cc - H_DIM));
#pragma unroll
        for (int j = 0; j < 2; ++j) {
            half8 v = *reinterpret_cast<const half8*>(srcp + j * 8);
            float f[8];
#pragma unroll
            for (int q = 0; q < 8; ++q) f[q] = (float)v[q];
            short8 hv, lv;
#pragma unroll
            for (int q = 0; q < 8; ++q) {
                ushort hh = f2bf(f[q]);
                hv[q] = (short)hh;
                lv[q] = (short)f2bf(f[q] - bf2f(hh));
            }
            uint chunk = (uint)((tid & 31) * 2 + j);
            uint byte = (uint)p * 1024 + ((chunk ^ (uint)(p & 7)) << 4);
            *(short8*)(cH + byte) = hv;
            *(short8*)(cL + byte) = lv;
        }
    }
    __syncthreads();

    f32x4 acc[4];
#pragma unroll
    for (int oi = 0; oi < 4; ++oi) acc[oi] = (f32x4){0.f, 0.f, 0.f, 0.f};

    for (int kt = 0; kt < 16; ++kt) {
        uint ab = (uint)col * 1024 + ((uint)((kt * 4 + kg) ^ (col & 7)) << 4);
        short8 Ah = *(const short8*)(cH + ab);
        short8 Al = *(const short8*)(cL + ab);
#pragma unroll
        for (int oi = 0; oi < 4; ++oi) {
            int g = kt * 32 + wv * 4 + oi;
            short8 Bh = wf[(g * 2 + 0) * 64 + lane];
            short8 Bl = wf[(g * 2 + 1) * 64 + lane];
            f32x4 a = acc[oi];
            a = __builtin_amdgcn_mfma_f32_16x16x32_bf16(Ah, Bh, a, 0, 0, 0);
            a = __builtin_amdgcn_mfma_f32_16x16x32_bf16(Ah, Bl, a, 0, 0, 0);
            a = __builtin_amdgcn_mfma_f32_16x16x32_bf16(Al, Bh, a, 0, 0, 0);
            a = __builtin_amdgcn_mfma_f32_16x16x32_bf16(Al, Bl, a, 0, 0, 0);
            acc[oi] = a;
        }
    }

    float val[4] = {0.f, 0.f, 0.f, 0.f};
#pragma unroll
    for (int oi = 0; oi < 4; ++oi) {
        int o = 64 * wv + oi * 16 + col;
        float b1o = b1f[o], w2o = W2[o];
#pragma unroll
        for (int rg = 0; rg < 4; ++rg) {
            float y = acc[oi][rg] + b1o;
            y = y > 0.f ? y : 0.f;
            val[rg] = fmaf(y, w2o, val[rg]);
        }
    }
#pragma unroll
    for (int rg = 0; rg < 4; ++rg) {
        float v = val[rg];
        v += __shfl_xor(v, 1, 64);
        v += __shfl_xor(v, 2, 64);
        v += __shfl_xor(v, 4, 64);
        v += __shfl_xor(v, 8, 64);
        val[rg] = v;
    }
    if (col == 0) {
#pragma unroll
        for (int rg = 0; rg < 4; ++rg) red[kg * 4 + rg][wv] = val[rg];
    }
    __syncthreads();
    if (tid < 16) {
        float s = 0.f;
#pragma unroll
        for (int w = 0; w < 8; w++) s += red[tid][w];
        s += b2f[0];
        outp[p0 + tid] = 1.f / (1.f + __expf(-s));
    }
}

extern "C" void kernel_launch(void* const* d_in, const int* in_sizes, int n_in,
                              void* d_out, int out_size, void* d_ws, size_t ws_size,
                              hipStream_t stream) {
    (void)in_sizes; (void)n_in; (void)out_size; (void)ws_size;
    const int*   drugs   = (const int*)d_in[0];
    const int*   targets = (const int*)d_in[1];
    const int*   nid     = (const int*)d_in[2];
    const int*   src     = (const int*)d_in[3];
    const int*   dst     = (const int*)d_in[4];
    const int*   ety     = (const int*)d_in[5];
    const float* nrm     = (const float*)d_in[6];
    const float* emb     = (const float*)d_in[7];
    const float* w1      = (const float*)d_in[8];
    const float* lw1     = (const float*)d_in[9];
    const float* b1      = (const float*)d_in[10];
    const float* w2      = (const float*)d_in[11];
    const float* lw2     = (const float*)d_in[12];
    const float* b2      = (const float*)d_in[13];
    const float* fc1W    = (const float*)d_in[14];
    const float* fc1b    = (const float*)d_in[15];
    const float* fc2W    = (const float*)d_in[16];
    const float* fc2b    = (const float*)d_in[17];
    float* outp = (float*)d_out;

    // ws layout — same offsets as round-10/11.
    char* ws = (char*)d_ws;
    ushort*   wfrag1  = (ushort*)  (ws);                 //    524,288
    ushort*   wfrag2  = (ushort*)  (ws + 524288);        //    524,288
    ushort*   lwfrag1 = (ushort*)  (ws + 1048576);       //    262,144
    ushort*   lwfrag2 = (ushort*)  (ws + 1310720);       //    262,144
    ushort*   fc1frag = (ushort*)  (ws + 1572864);       //  1,048,576
    _Float16* hA      = (_Float16*)(ws + 2621440);       // 10,240,000 used
    _Float16* hB      = (_Float16*)(ws + 23101440);      // 10,240,000 used
    int*      segend  = (int*)     (ws + 43581440);      //  1,280,000
    int*      bs      = (int*)     (ws + 44861440);      //      1,024
    uint*     es      = (uint*)    (ws + 44862464);      //  1,600,000 -> end 46,462,464

    k_prep_all<<<320 + ZBLOCKS, 256, 0, stream>>>(w1, w2, lw1, lw2, fc1W,
                                                  wfrag1, wfrag2, lwfrag1, lwfrag2,
                                                  fc1frag, segend);
    k_gather <<<5000, 256, 0, stream>>>(emb, nid, hA);
    k_count  <<<(E_EDGES + 255) / 256, 256, 0, stream>>>(dst, ety, segend);
    k_scan1  <<<NSCAN_BLOCKS, 256, 0, stream>>>(segend, bs);
    k_scan2  <<<1, 256, 0, stream>>>(bs);
    k_scan3  <<<(NBINS + 255) / 256, 256, 0, stream>>>(segend, bs);
    k_scatter<<<(E_EDGES + 255) / 256, 256, 0, stream>>>(src, dst, ety, nrm, segend, es);
    k_layer  <<<NT_BLOCKS, 512, 0, stream>>>(hA, es, segend, wfrag1, lwfrag1, b1, hB);
    k_layer  <<<NT_BLOCKS, 512, 0, stream>>>(hB, es, segend, wfrag2, lwfrag2, b2, hA);
    k_mlp    <<<NPAIRS / 16, 512, 0, stream>>>(hA, drugs, targets, fc1frag, fc1b, fc2W, fc2b, outp);
}

// Round 13
// 295.416 us; speedup vs baseline: 1.5274x; 1.5274x over previous
//
#include <hip/hip_runtime.h>
#include <math.h>

typedef __attribute__((ext_vector_type(8))) short short8;
typedef __attribute__((ext_vector_type(4))) float f32x4;
typedef __attribute__((ext_vector_type(4))) _Float16 half4;
typedef __attribute__((ext_vector_type(8))) _Float16 half8;

#define N_SUBN   20000
#define E_EDGES  400000
#define R_REL    16
#define H_DIM    256
#define NBINS    (N_SUBN * R_REL)          // 320000 (dst,rel) buckets
#define SCAN_CHUNK 2048
#define NSCAN_BLOCKS ((NBINS + SCAN_CHUNK - 1) / SCAN_CHUNK)   // 157
#define NPAIRS   4096
#define TILE_N   32
#define NT_BLOCKS (N_SUBN / TILE_N)                            // 625 exact
#define D2       512
#define ECAP     1024                      // LDS edge-cache capacity (avg ~640/block)

// ---- bf16 hi/lo split helpers (RNE) ----
__device__ __forceinline__ ushort f2bf(float x) {
    uint u = __float_as_uint(x);
    u += 0x7fffu + ((u >> 16) & 1u);
    return (ushort)(u >> 16);
}
__device__ __forceinline__ float bf2f(ushort h) {
    return __uint_as_float(((uint)h) << 16);
}

// ---------------- CSR build over bin = dst*R + etype ----------------
__global__ void k_count(const int* __restrict__ dst, const int* __restrict__ ety,
                        int* __restrict__ cnt) {
    int e = blockIdx.x * 256 + threadIdx.x;
    if (e < E_EDGES) atomicAdd(&cnt[dst[e] * R_REL + ety[e]], 1);
}

__global__ void k_scan1(int* __restrict__ data, int* __restrict__ bs) {
    __shared__ int ts[256];
    int base = blockIdx.x * SCAN_CHUNK + threadIdx.x * 8;
    int v[8]; int s = 0;
#pragma unroll
    for (int j = 0; j < 8; j++) {
        int idx = base + j;
        v[j] = (idx < NBINS) ? data[idx] : 0;
        s += v[j];
    }
    ts[threadIdx.x] = s;
    __syncthreads();
    for (int off = 1; off < 256; off <<= 1) {
        int add = (threadIdx.x >= (unsigned)off) ? ts[threadIdx.x - off] : 0;
        __syncthreads();
        ts[threadIdx.x] += add;
        __syncthreads();
    }
    int excl = ts[threadIdx.x] - s;
    if (threadIdx.x == 255) bs[blockIdx.x] = ts[255];
    int run = excl;
#pragma unroll
    for (int j = 0; j < 8; j++) {
        int idx = base + j;
        if (idx < NBINS) data[idx] = run;
        run += v[j];
    }
}

__global__ void k_scan2(int* __restrict__ bs) {
    __shared__ int ls[NSCAN_BLOCKS];
    if (threadIdx.x < NSCAN_BLOCKS) ls[threadIdx.x] = bs[threadIdx.x];
    __syncthreads();
    if (threadIdx.x == 0) {
        int run = 0;
        for (int i = 0; i < NSCAN_BLOCKS; i++) { int t = ls[i]; ls[i] = run; run += t; }
    }
    __syncthreads();
    if (threadIdx.x < NSCAN_BLOCKS) bs[threadIdx.x] = ls[threadIdx.x];
}

__global__ void k_scan3(int* __restrict__ data, const int* __restrict__ bs) {
    int idx = blockIdx.x * 256 + threadIdx.x;
    if (idx < NBINS) data[idx] = data[idx] + bs[idx / SCAN_CHUNK];
}

// scatter increments segend in place: post-scatter segend[bin] = END of bin,
// beg(bin) = (bin==0) ? 0 : segend[bin-1]. Edge packed: (src<<17) | norm_q17.
__global__ void k_scatter(const int* __restrict__ src, const int* __restrict__ dst,
                          const int* __restrict__ ety, const float* __restrict__ nrm,
                          int* __restrict__ segend, uint* __restrict__ es) {
    int e = blockIdx.x * 256 + threadIdx.x;
    if (e >= E_EDGES) return;
    int bin = dst[e] * R_REL + ety[e];
    int pos = atomicAdd(&segend[bin], 1);
    float n = nrm[e];
    uint q = (uint)fminf(n * 131072.f + 0.5f, 131071.f);
    es[pos] = ((uint)src[e] << 17) | q;
}

// ---------------- combined pre-pack + segend zero + gather (one dispatch) -------
__device__ __forceinline__ void prep_w_body(const float* __restrict__ w,
                                            ushort* __restrict__ wfrag, int t) {
    int lane = t & 63, f = t >> 6;
    int ot = f & 1, rb = f >> 1;              // rb = r*8+b
    int kbase = (lane >> 4) * 8, n = ot * 16 + (lane & 15);
    ushort hv[8], lv[8];
#pragma unroll
    for (int j = 0; j < 8; j++) {
        float x = w[(size_t)(rb * 32 + kbase + j) * 32 + n];
        ushort h = f2bf(x);
        ushort l = f2bf(x - bf2f(h));
        hv[j] = h; lv[j] = l;
    }
    *reinterpret_cast<short8*>(wfrag + ((size_t)(f * 2 + 0) * 64 + lane) * 8) =
        *reinterpret_cast<short8*>(hv);
    *reinterpret_cast<short8*>(wfrag + ((size_t)(f * 2 + 1) * 64 + lane) * 8) =
        *reinterpret_cast<short8*>(lv);
}

__device__ __forceinline__ void prep_lw_body(const float* __restrict__ lw,
                                             ushort* __restrict__ lwfrag, int t) {
    int lane = t & 63, g = t >> 6;
    int kt = g >> 4, ot = g & 15;
    int kbase = kt * 32 + (lane >> 4) * 8, n = ot * 16 + (lane & 15);
    ushort hv[8], lv[8];
#pragma unroll
    for (int j = 0; j < 8; j++) {
        float x = lw[(size_t)(kbase + j) * H_DIM + n];
        ushort h = f2bf(x);
        ushort l = f2bf(x - bf2f(h));
        hv[j] = h; lv[j] = l;
    }
    *reinterpret_cast<short8*>(lwfrag + ((size_t)(g * 2 + 0) * 64 + lane) * 8) =
        *reinterpret_cast<short8*>(hv);
    *reinterpret_cast<short8*>(lwfrag + ((size_t)(g * 2 + 1) * 64 + lane) * 8) =
        *reinterpret_cast<short8*>(lv);
}

__device__ __forceinline__ void prep_fc1_body(const float* __restrict__ w,
                                              ushort* __restrict__ wfrag, int t) {
    int lane = t & 63, g = t >> 6;
    int kt = g >> 5, ot = g & 31;
    int kbase = kt * 32 + (lane >> 4) * 8, n = ot * 16 + (lane & 15);
    ushort hv[8], lv[8];
#pragma unroll
    for (int j = 0; j < 8; j++) {
        float x = w[(size_t)(kbase + j) * D2 + n];
        ushort h = f2bf(x);
        ushort l = f2bf(x - bf2f(h));
        hv[j] = h; lv[j] = l;
    }
    *reinterpret_cast<short8*>(wfrag + ((size_t)(g * 2 + 0) * 64 + lane) * 8) =
        *reinterpret_cast<short8*>(hv);
    *reinterpret_cast<short8*>(wfrag + ((size_t)(g * 2 + 1) * 64 + lane) * 8) =
        *reinterpret_cast<short8*>(lv);
}

#define ZBLOCKS ((NBINS + 255) / 256)       // 1250
#define GBLOCKS 5000                        // gather: 20000 nodes * 64 f16x4 slots
#define PREP_GRID (320 + ZBLOCKS + GBLOCKS)

__global__ void k_prep_all(const float* __restrict__ w1, const float* __restrict__ w2,
                           const float* __restrict__ lw1, const float* __restrict__ lw2,
                           const float* __restrict__ fc1W,
                           const float* __restrict__ emb, const int* __restrict__ nid,
                           ushort* __restrict__ wfrag1, ushort* __restrict__ wfrag2,
                           ushort* __restrict__ lwfrag1, ushort* __restrict__ lwfrag2,
                           ushort* __restrict__ fc1frag, int* __restrict__ segend,
                           _Float16* __restrict__ h0) {
    int b = blockIdx.x, tid = threadIdx.x;
    if (b < 64)        prep_w_body(w1, wfrag1, b * 256 + tid);
    else if (b < 128)  prep_w_body(w2, wfrag2, (b - 64) * 256 + tid);
    else if (b < 160)  prep_lw_body(lw1, lwfrag1, (b - 128) * 256 + tid);
    else if (b < 192)  prep_lw_body(lw2, lwfrag2, (b - 160) * 256 + tid);
    else if (b < 320)  prep_fc1_body(fc1W, fc1frag, (b - 192) * 256 + tid);
    else if (b < 320 + ZBLOCKS) {
        int i = (b - 320) * 256 + tid;
        if (i < NBINS) segend[i] = 0;
    } else {
        int t = (b - 320 - ZBLOCKS) * 256 + tid;
        int node = t >> 6, c = (t & 63) << 2;
        if (node < N_SUBN) {
            const float4 s = *reinterpret_cast<const float4*>(
                emb + (size_t)nid[node] * H_DIM + c);
            half4 d = {(_Float16)s.x, (_Float16)s.y, (_Float16)s.z, (_Float16)s.w};
            *reinterpret_cast<half4*>(h0 + (size_t)node * H_DIM + c) = d;
        }
    }
}

// ---------------- fused RGCN-BDD layer (MFMA, bf16 hi/lo 3-term) ----------------
// Round-11 structure (TILE 32, 512 thr = 8 waves, LDS edge cache, single agg
// buffer, 2 barriers/rel, fp16 h) with IN-PHASE BATCHED aggregation: the first
// 2 edges of each of the wave's 4 chains are loaded branchless (clamped address,
// zero norm when invalid) in ONE batch of 8 independent row loads — one exposed
// load-round instead of ~2.5. deg>=3 tails (13% of bins) take the wave-uniform
// serial path. No prefetch state crosses the MFMA phase (round-12 lesson).
__global__ __launch_bounds__(512) void k_layer(
    const _Float16* __restrict__ hin, const uint* __restrict__ es,
    const int* __restrict__ segend,
    const ushort* __restrict__ wfrag, const ushort* __restrict__ lwfrag,
    const float* __restrict__ bias, _Float16* __restrict__ hout) {
    __shared__ __align__(16) ushort aggH[TILE_N * H_DIM];
    __shared__ __align__(16) ushort aggLo[TILE_N * H_DIM];
    __shared__ int lofs[TILE_N * R_REL + 1];
    __shared__ uint les[ECAP];
    char* cH = (char*)aggH;
    char* cL = (char*)aggLo;
    const int n0 = blockIdx.x * TILE_N;
    const int tid = threadIdx.x;
    const int lane = tid & 63, wv = tid >> 6;
    const int col = lane & 15, kg = lane >> 4;
    const short8* wf  = (const short8*)wfrag;
    const short8* lwf = (const short8*)lwfrag;
    const uint laneoff = (uint)(lane << 2);     // element offset (4 fp16 per lane)
    const int t0 = 4 * wv;

    {   // block-local offset table (coalesced, once)
        const int base = n0 * R_REL;
        for (int j = tid; j < TILE_N * R_REL + 1; j += 512) {
            int g = base + j - 1;
            lofs[j] = (g < 0) ? 0 : segend[g];
        }
    }
    __syncthreads();
    const int ebase = lofs[0];
    const int elim  = min(lofs[TILE_N * R_REL] - ebase, ECAP);
    for (int j = tid; j < elim; j += 512) les[j] = es[ebase + j];
    __syncthreads();   // les published

    auto eget = [&](int e) -> uint {        // valid e only
        int i = e - ebase;
        return (i < ECAP) ? les[i] : es[e];
    };
    // clamped fetch: always returns a word from a VALID edge slot of this block
    auto wget = [&](int e, int dlim) -> uint {
        int idx = min(e, dlim - 1);
        idx = max(idx, ebase);
        return eget(idx);
    };
    auto rowload = [&](uint pk) -> half4 {
        return *reinterpret_cast<const half4*>(hin + (size_t)(pk >> 17) * H_DIM + laneoff);
    };

    f32x4 acc[2][2];
#pragma unroll
    for (int mt = 0; mt < 2; ++mt)
#pragma unroll
        for (int ot = 0; ot < 2; ++ot) acc[mt][ot] = (f32x4){0.f, 0.f, 0.f, 0.f};

    for (int r = 0; r < R_REL; ++r) {
        __syncthreads();   // previous MFMA reads done before agg overwrite
        int e0 = lofs[(t0 + 0) * R_REL + r], d0 = lofs[(t0 + 0) * R_REL + r + 1];
        int e1 = lofs[(t0 + 1) * R_REL + r], d1 = lofs[(t0 + 1) * R_REL + r + 1];
        int e2 = lofs[(t0 + 2) * R_REL + r], d2 = lofs[(t0 + 2) * R_REL + r + 1];
        int e3 = lofs[(t0 + 3) * R_REL + r], d3 = lofs[(t0 + 3) * R_REL + r + 1];
        // ---- batch: edge words (LDS) then 8 independent row loads ----
        uint w0a = wget(e0, d0),     w0b = wget(e0 + 1, d0);
        uint w1a = wget(e1, d1),     w1b = wget(e1 + 1, d1);
        uint w2a = wget(e2, d2),     w2b = wget(e2 + 1, d2);
        uint w3a = wget(e3, d3),     w3b = wget(e3 + 1, d3);
        half4 x0a = rowload(w0a), x0b = rowload(w0b);
        half4 x1a = rowload(w1a), x1b = rowload(w1b);
        half4 x2a = rowload(w2a), x2b = rowload(w2b);
        half4 x3a = rowload(w3a), x3b = rowload(w3b);
        float n0a = (e0     < d0) ? (float)(w0a & 0x1FFFFu) * (1.f / 131072.f) : 0.f;
        float n0b = (e0 + 1 < d0) ? (float)(w0b & 0x1FFFFu) * (1.f / 131072.f) : 0.f;
        float n1a = (e1     < d1) ? (float)(w1a & 0x1FFFFu) * (1.f / 131072.f) : 0.f;
        float n1b = (e1 + 1 < d1) ? (float)(w1b & 0x1FFFFu) * (1.f / 131072.f) : 0.f;
        float n2a = (e2     < d2) ? (float)(w2a & 0x1FFFFu) * (1.f / 131072.f) : 0.f;
        float n2b = (e2 + 1 < d2) ? (float)(w2b & 0x1FFFFu) * (1.f / 131072.f) : 0.f;
        float n3a = (e3     < d3) ? (float)(w3a & 0x1FFFFu) * (1.f / 131072.f) : 0.f;
        float n3b = (e3 + 1 < d3) ? (float)(w3b & 0x1FFFFu) * (1.f / 131072.f) : 0.f;
        float4 a0, a1, a2, a3;
        a0.x = fmaf((float)x0a[0], n0a, (float)x0b[0] * n0b);
        a0.y = fmaf((float)x0a[1], n0a, (float)x0b[1] * n0b);
        a0.z = fmaf((float)x0a[2], n0a, (float)x0b[2] * n0b);
        a0.w = fmaf((float)x0a[3], n0a, (float)x0b[3] * n0b);
        a1.x = fmaf((float)x1a[0], n1a, (float)x1b[0] * n1b);
        a1.y = fmaf((float)x1a[1], n1a, (float)x1b[1] * n1b);
        a1.z = fmaf((float)x1a[2], n1a, (float)x1b[2] * n1b);
        a1.w = fmaf((float)x1a[3], n1a, (float)x1b[3] * n1b);
        a2.x = fmaf((float)x2a[0], n2a, (float)x2b[0] * n2b);
        a2.y = fmaf((float)x2a[1], n2a, (float)x2b[1] * n2b);
        a2.z = fmaf((float)x2a[2], n2a, (float)x2b[2] * n2b);
        a2.w = fmaf((float)x2a[3], n2a, (float)x2b[3] * n2b);
        a3.x = fmaf((float)x3a[0], n3a, (float)x3b[0] * n3b);
        a3.y = fmaf((float)x3a[1], n3a, (float)x3b[1] * n3b);
        a3.z = fmaf((float)x3a[2], n3a, (float)x3b[2] * n3b);
        a3.w = fmaf((float)x3a[3], n3a, (float)x3b[3] * n3b);
        // ---- rare deg>=3 tails (wave-uniform branches) ----
        for (int e = e0 + 2; e < d0; ++e) {
            uint pk = eget(e); half4 x = rowload(pk);
            float nm = (float)(pk & 0x1FFFFu) * (1.f / 131072.f);
            a0.x = fmaf((float)x[0], nm, a0.x); a0.y = fmaf((float)x[1], nm, a0.y);
            a0.z = fmaf((float)x[2], nm, a0.z); a0.w = fmaf((float)x[3], nm, a0.w);
        }
        for (int e = e1 + 2; e < d1; ++e) {
            uint pk = eget(e); half4 x = rowload(pk);
            float nm = (float)(pk & 0x1FFFFu) * (1.f / 131072.f);
            a1.x = fmaf((float)x[0], nm, a1.x); a1.y = fmaf((float)x[1], nm, a1.y);
            a1.z = fmaf((float)x[2], nm, a1.z); a1.w = fmaf((float)x[3], nm, a1.w);
        }
        for (int e = e2 + 2; e < d2; ++e) {
            uint pk = eget(e); half4 x = rowload(pk);
            float nm = (float)(pk & 0x1FFFFu) * (1.f / 131072.f);
            a2.x = fmaf((float)x[0], nm, a2.x); a2.y = fmaf((float)x[1], nm, a2.y);
            a2.z = fmaf((float)x[2], nm, a2.z); a2.w = fmaf((float)x[3], nm, a2.w);
        }
        for (int e = e3 + 2; e < d3; ++e) {
            uint pk = eget(e); half4 x = rowload(pk);
            float nm = (float)(pk & 0x1FFFFu) * (1.f / 131072.f);
            a3.x = fmaf((float)x[0], nm, a3.x); a3.y = fmaf((float)x[1], nm, a3.y);
            a3.z = fmaf((float)x[2], nm, a3.z); a3.w = fmaf((float)x[3], nm, a3.w);
        }
        // ---- split + store rows to swizzled LDS planes ----
#pragma unroll
        for (int i = 0; i < 4; ++i) {
            float4 av = (i == 0) ? a0 : (i == 1) ? a1 : (i == 2) ? a2 : a3;
            int t = t0 + i;
            ushort h0 = f2bf(av.x), h1 = f2bf(av.y), h2 = f2bf(av.z), h3 = f2bf(av.w);
            uint2 ph = make_uint2((uint)h0 | ((uint)h1 << 16), (uint)h2 | ((uint)h3 << 16));
            uint2 pl = make_uint2(
                (uint)f2bf(av.x - bf2f(h0)) | ((uint)f2bf(av.y - bf2f(h1)) << 16),
                (uint)f2bf(av.z - bf2f(h2)) | ((uint)f2bf(av.w - bf2f(h3)) << 16));
            uint byte = (uint)(t * 512) + ((((lane >> 1) ^ (t & 7)) << 4) | ((lane & 1) << 3));
            *(uint2*)(cH + byte) = ph;
            *(uint2*)(cL + byte) = pl;
        }
        __syncthreads();   // agg stores visible
        // ---- transform rel r: wave wv owns b-block wv ----
#pragma unroll
        for (int ot = 0; ot < 2; ++ot) {
            int f = (r * 8 + wv) * 2 + ot;
            short8 Bh = wf[(f * 2 + 0) * 64 + lane];
            short8 Bl = wf[(f * 2 + 1) * 64 + lane];
#pragma unroll
            for (int mt = 0; mt < 2; ++mt) {
                int row = mt * 16 + col;
                uint ab = (uint)(row * 512) + ((uint)((wv * 4 + kg) ^ (row & 7)) << 4);
                short8 Ah = *(const short8*)(cH + ab);
                short8 Al = *(const short8*)(cL + ab);
                f32x4 a = acc[mt][ot];
                a = __builtin_amdgcn_mfma_f32_16x16x32_bf16(Ah, Bh, a, 0, 0, 0);
                a = __builtin_amdgcn_mfma_f32_16x16x32_bf16(Ah, Bl, a, 0, 0, 0);
                a = __builtin_amdgcn_mfma_f32_16x16x32_bf16(Al, Bh, a, 0, 0, 0);
                acc[mt][ot] = a;
            }
        }
    }

    // ---- self-loop: restage h tile as hi/lo, K=256 MFMA sweep ----
    __syncthreads();
#pragma unroll
    for (int i = 0; i < 4; ++i) {
        int t = t0 + i;
        const half4 xh = *reinterpret_cast<const half4*>(
            hin + (size_t)(n0 + t) * H_DIM + laneoff);
        float4 xv = make_float4((float)xh[0], (float)xh[1], (float)xh[2], (float)xh[3]);
        ushort h0 = f2bf(xv.x), h1 = f2bf(xv.y), h2 = f2bf(xv.z), h3 = f2bf(xv.w);
        uint2 ph = make_uint2((uint)h0 | ((uint)h1 << 16), (uint)h2 | ((uint)h3 << 16));
        uint2 pl = make_uint2(
            (uint)f2bf(xv.x - bf2f(h0)) | ((uint)f2bf(xv.y - bf2f(h1)) << 16),
            (uint)f2bf(xv.z - bf2f(h2)) | ((uint)f2bf(xv.w - bf2f(h3)) << 16));
        uint byte = (uint)(t * 512) + ((((lane >> 1) ^ (t & 7)) << 4) | ((lane & 1) << 3));
        *(uint2*)(cH + byte) = ph;
        *(uint2*)(cL + byte) = pl;
    }
    __syncthreads();
#pragma unroll
    for (int kt = 0; kt < 8; ++kt) {
#pragma unroll
        for (int ot = 0; ot < 2; ++ot) {
            int g = kt * 16 + 2 * wv + ot;
            short8 Bh = lwf[(g * 2 + 0) * 64 + lane];
            short8 Bl = lwf[(g * 2 + 1) * 64 + lane];
#pragma unroll
            for (int mt = 0; mt < 2; ++mt) {
                int row = mt * 16 + col;
                uint ab = (uint)(row * 512) + ((uint)((kt * 4 + kg) ^ (row & 7)) << 4);
                short8 Ah = *(const short8*)(cH + ab);
                short8 Al = *(const short8*)(cL + ab);
                f32x4 a = acc[mt][ot];
                a = __builtin_amdgcn_mfma_f32_16x16x32_bf16(Ah, Bh, a, 0, 0, 0);
                a = __builtin_amdgcn_mfma_f32_16x16x32_bf16(Ah, Bl, a, 0, 0, 0);
                a = __builtin_amdgcn_mfma_f32_16x16x32_bf16(Al, Bh, a, 0, 0, 0);
                acc[mt][ot] = a;
            }
        }
    }

    // ---- epilogue: C/D layout col=lane&15, row=(lane>>4)*4+reg; fp16 store ----
#pragma unroll
    for (int mt = 0; mt < 2; ++mt) {
        int nbase = n0 + mt * 16 + kg * 4;
#pragma unroll
        for (int ot = 0; ot < 2; ++ot) {
            int o = 32 * wv + ot * 16 + col;
            float bo = bias[o];
#pragma unroll
            for (int rg = 0; rg < 4; ++rg)
                hout[(size_t)(nbase + rg) * H_DIM + o] = (_Float16)(acc[mt][ot][rg] + bo);
        }
    }
}

// ---------------- fused concat + fc1(MFMA) + relu + fc2 + sigmoid ----------------
__global__ __launch_bounds__(512) void k_mlp(
    const _Float16* __restrict__ h, const int* __restrict__ drugs,
    const int* __restrict__ targets,
    const ushort* __restrict__ fc1frag, const float* __restrict__ b1f,
    const float* __restrict__ W2, const float* __restrict__ b2f,
    float* __restrict__ outp) {
    __shared__ __align__(16) ushort xH[16 * D2];
    __shared__ __align__(16) ushort xL[16 * D2];
    __shared__ float red[16][8];
    char* cH = (char*)xH;
    char* cL = (char*)xL;
    const int tid = threadIdx.x;
    const int lane = tid & 63, wv = tid >> 6;
    const int col = lane & 15, kg = lane >> 4;
    const int p0 = blockIdx.x * 16;
    const short8* wf = (const short8*)fc1frag;

    {   // stage X = [h[drug] | h[target]] (fp16) as bf16 hi/lo, swizzled
        int p = tid >> 5;
        int cc = (tid & 31) * 16;
        int di = drugs[p0 + p], ti = targets[p0 + p];
        const _Float16* srcp = (cc < H_DIM) ? (h + (size_t)di * H_DIM + cc)
                                            : (h + (size_t)ti * H_DIM + (cc - H_DIM));
#pragma unroll
        for (int j = 0; j < 2; ++j) {
            half8 v = *reinterpret_cast<const half8*>(srcp + j * 8);
            float f[8];
#pragma unroll
            for (int q = 0; q < 8; ++q) f[q] = (float)v[q];
            short8 hv, lv;
#pragma unroll
            for (int q = 0; q < 8; ++q) {
                ushort hh = f2bf(f[q]);
                hv[q] = (short)hh;
                lv[q] = (short)f2bf(f[q] - bf2f(hh));
            }
            uint chunk = (uint)((tid & 31) * 2 + j);
            uint byte = (uint)p * 1024 + ((chunk ^ (uint)(p & 7)) << 4);
            *(short8*)(cH + byte) = hv;
            *(short8*)(cL + byte) = lv;
        }
    }
    __syncthreads();

    f32x4 acc[4];
#pragma unroll
    for (int oi = 0; oi < 4; ++oi) acc[oi] = (f32x4){0.f, 0.f, 0.f, 0.f};

    for (int kt = 0; kt < 16; ++kt) {
        uint ab = (uint)col * 1024 + ((uint)((kt * 4 + kg) ^ (col & 7)) << 4);
        short8 Ah = *(const short8*)(cH + ab);
        short8 Al = *(const short8*)(cL + ab);
#pragma unroll
        for (int oi = 0; oi < 4; ++oi) {
            int g = kt * 32 + wv * 4 + oi;
            short8 Bh = wf[(g * 2 + 0) * 64 + lane];
            short8 Bl = wf[(g * 2 + 1) * 64 + lane];
            f32x4 a = acc[oi];
            a = __builtin_amdgcn_mfma_f32_16x16x32_bf16(Ah, Bh, a, 0, 0, 0);
            a = __builtin_amdgcn_mfma_f32_16x16x32_bf16(Ah, Bl, a, 0, 0, 0);
            a = __builtin_amdgcn_mfma_f32_16x16x32_bf16(Al, Bh, a, 0, 0, 0);
            a = __builtin_amdgcn_mfma_f32_16x16x32_bf16(Al, Bl, a, 0, 0, 0);
            acc[oi] = a;
        }
    }

    float val[4] = {0.f, 0.f, 0.f, 0.f};
#pragma unroll
    for (int oi = 0; oi < 4; ++oi) {
        int o = 64 * wv + oi * 16 + col;
        float b1o = b1f[o], w2o = W2[o];
#pragma unroll
        for (int rg = 0; rg < 4; ++rg) {
            float y = acc[oi][rg] + b1o;
            y = y > 0.f ? y : 0.f;
            val[rg] = fmaf(y, w2o, val[rg]);
        }
    }
#pragma unroll
    for (int rg = 0; rg < 4; ++rg) {
        float v = val[rg];
        v += __shfl_xor(v, 1, 64);
        v += __shfl_xor(v, 2, 64);
        v += __shfl_xor(v, 4, 64);
        v += __shfl_xor(v, 8, 64);
        val[rg] = v;
    }
    if (col == 0) {
#pragma unroll
        for (int rg = 0; rg < 4; ++rg) red[kg * 4 + rg][wv] = val[rg];
    }
    __syncthreads();
    if (tid < 16) {
        float s = 0.f;
#pragma unroll
        for (int w = 0; w < 8; w++) s += red[tid][w];
        s += b2f[0];
        outp[p0 + tid] = 1.f / (1.f + __expf(-s));
    }
}

extern "C" void kernel_launch(void* const* d_in, const int* in_sizes, int n_in,
                              void* d_out, int out_size, void* d_ws, size_t ws_size,
                              hipStream_t stream) {
    (void)in_sizes; (void)n_in; (void)out_size; (void)ws_size;
    const int*   drugs   = (const int*)d_in[0];
    const int*   targets = (const int*)d_in[1];
    const int*   nid     = (const int*)d_in[2];
    const int*   src     = (const int*)d_in[3];
    const int*   dst     = (const int*)d_in[4];
    const int*   ety     = (const int*)d_in[5];
    const float* nrm     = (const float*)d_in[6];
    const float* emb     = (const float*)d_in[7];
    const float* w1      = (const float*)d_in[8];
    const float* lw1     = (const float*)d_in[9];
    const float* b1      = (const float*)d_in[10];
    const float* w2      = (const float*)d_in[11];
    const float* lw2     = (const float*)d_in[12];
    const float* b2      = (const float*)d_in[13];
    const float* fc1W    = (const float*)d_in[14];
    const float* fc1b    = (const float*)d_in[15];
    const float* fc2W    = (const float*)d_in[16];
    const float* fc2b    = (const float*)d_in[17];
    float* outp = (float*)d_out;

    // ws layout — same offsets as rounds 10-12.
    char* ws = (char*)d_ws;
    ushort*   wfrag1  = (ushort*)  (ws);                 //    524,288
    ushort*   wfrag2  = (ushort*)  (ws + 524288);        //    524,288
    ushort*   lwfrag1 = (ushort*)  (ws + 1048576);       //    262,144
    ushort*   lwfrag2 = (ushort*)  (ws + 1310720);       //    262,144
    ushort*   fc1frag = (ushort*)  (ws + 1572864);       //  1,048,576
    _Float16* hA      = (_Float16*)(ws + 2621440);       // 10,240,000 used
    _Float16* hB      = (_Float16*)(ws + 23101440);      // 10,240,000 used
    int*      segend  = (int*)     (ws + 43581440);      //  1,280,000
    int*      bs      = (int*)     (ws + 44861440);      //      1,024
    uint*     es      = (uint*)    (ws + 44862464);      //  1,600,000 -> end 46,462,464

    k_prep_all<<<PREP_GRID, 256, 0, stream>>>(w1, w2, lw1, lw2, fc1W, emb, nid,
                                              wfrag1, wfrag2, lwfrag1, lwfrag2,
                                              fc1frag, segend, hA);
    k_count  <<<(E_EDGES + 255) / 256, 256, 0, stream>>>(dst, ety, segend);
    k_scan1  <<<NSCAN_BLOCKS, 256, 0, stream>>>(segend, bs);
    k_scan2  <<<1, 256, 0, stream>>>(bs);
    k_scan3  <<<(NBINS + 255) / 256, 256, 0, stream>>>(segend, bs);
    k_scatter<<<(E_EDGES + 255) / 256, 256, 0, stream>>>(src, dst, ety, nrm, segend, es);
    k_layer  <<<NT_BLOCKS, 512, 0, stream>>>(hA, es, segend, wfrag1, lwfrag1, b1, hB);
    k_layer  <<<NT_BLOCKS, 512, 0, stream>>>(hB, es, segend, wfrag2, lwfrag2, b2, hA);
    k_mlp    <<<NPAIRS / 16, 512, 0, stream>>>(hA, drugs, targets, fc1frag, fc1b, fc2W, fc2b, outp);
}